// Round 1
// baseline (921.303 us; speedup 1.0000x reference)
//
#include <hip/hip_runtime.h>

#define CH 64
#define BN_EPS 1e-5f

__device__ __forceinline__ float silu_f(float x) { return x / (1.0f + __expf(-x)); }

// ---------------------------------------------------------------------------
// Kernel: h = x @ Win + bin ; accumulate per-channel sum/sumsq for BN1
// ---------------------------------------------------------------------------
__global__ __launch_bounds__(256) void k_lin_in(
    const float* __restrict__ x, const float* __restrict__ Win, const float* __restrict__ bin,
    float* __restrict__ h, float* __restrict__ ssum, float* __restrict__ ssq, int N)
{
    __shared__ float xt[64 * 64];
    __shared__ float Wl[64 * 64];
    __shared__ float red[2][4][64];
    const int t = threadIdx.x, c = t & 63, g = t >> 6;
    const int row0 = blockIdx.x * 64;

    for (int i = t; i < 64 * 64; i += 256) {
        int r = i >> 6, cc = i & 63;
        int gr = row0 + r;
        xt[i] = (gr < N) ? x[(size_t)gr * CH + cc] : 0.0f;
        Wl[i] = Win[i];
    }
    __syncthreads();

    float acc[16];
    const float b = bin[c];
#pragma unroll
    for (int i = 0; i < 16; ++i) acc[i] = b;
    for (int k = 0; k < 64; ++k) {
        float w = Wl[k * 64 + c];
#pragma unroll
        for (int i = 0; i < 16; ++i) acc[i] += xt[(g * 16 + i) * 64 + k] * w;
    }
    float s = 0.0f, ss = 0.0f;
#pragma unroll
    for (int i = 0; i < 16; ++i) {
        int gr = row0 + g * 16 + i;
        if (gr < N) {
            h[(size_t)gr * CH + c] = acc[i];
            s += acc[i];
            ss += acc[i] * acc[i];
        }
    }
    red[0][g][c] = s;
    red[1][g][c] = ss;
    __syncthreads();
    if (g == 0) {
        atomicAdd(&ssum[c], red[0][0][c] + red[0][1][c] + red[0][2][c] + red[0][3][c]);
        atomicAdd(&ssq[c],  red[1][0][c] + red[1][1][c] + red[1][2][c] + red[1][3][c]);
    }
}

// ---------------------------------------------------------------------------
// Kernel: finalize BN scale/shift  (scale = g*rsqrt(var+eps), shift = b - mu*scale)
// ---------------------------------------------------------------------------
__global__ void k_stats(const float* __restrict__ ssum, const float* __restrict__ ssq,
                        const float* __restrict__ gamma, const float* __restrict__ beta,
                        float* __restrict__ scale, float* __restrict__ shift, int N)
{
    int c = threadIdx.x;
    float inv = 1.0f / (float)N;
    float mu = ssum[c] * inv;
    float var = ssq[c] * inv - mu * mu;
    float sc = gamma[c] * rsqrtf(var + BN_EPS);
    scale[c] = sc;
    shift[c] = beta[c] - mu * sc;
}

// ---------------------------------------------------------------------------
// Kernel: x1 = silu(h*scale+shift); v = x1@Wv; k = x1@Wk; q = x1@Wq
// ---------------------------------------------------------------------------
__global__ __launch_bounds__(256) void k_vkq(
    const float* __restrict__ h, const float* __restrict__ scale, const float* __restrict__ shift,
    const float* __restrict__ Wv, const float* __restrict__ Wk, const float* __restrict__ Wq,
    float* __restrict__ vv, float* __restrict__ kk, float* __restrict__ qq, int N)
{
    __shared__ float xt[64 * 64];
    __shared__ float Wl[2][64 * 64];
    const int t = threadIdx.x, c = t & 63, g = t >> 6;
    const int row0 = blockIdx.x * 64;

    for (int i = t; i < 64 * 64; i += 256) {
        int r = i >> 6, cc = i & 63;
        int gr = row0 + r;
        float hv = (gr < N) ? h[(size_t)gr * CH + cc] : 0.0f;
        xt[i] = silu_f(hv * scale[cc] + shift[cc]);
        Wl[0][i] = Wv[i];
        Wl[1][i] = Wk[i];
    }
    __syncthreads();

    // v and k
    for (int m = 0; m < 2; ++m) {
        float acc[16];
#pragma unroll
        for (int i = 0; i < 16; ++i) acc[i] = 0.0f;
        for (int k = 0; k < 64; ++k) {
            float w = Wl[m][k * 64 + c];
#pragma unroll
            for (int i = 0; i < 16; ++i) acc[i] += xt[(g * 16 + i) * 64 + k] * w;
        }
        float* o = (m == 0) ? vv : kk;
#pragma unroll
        for (int i = 0; i < 16; ++i) {
            int gr = row0 + g * 16 + i;
            if (gr < N) o[(size_t)gr * CH + c] = acc[i];
        }
    }
    __syncthreads();
    for (int i = t; i < 64 * 64; i += 256) Wl[0][i] = Wq[i];
    __syncthreads();
    {
        float acc[16];
#pragma unroll
        for (int i = 0; i < 16; ++i) acc[i] = 0.0f;
        for (int k = 0; k < 64; ++k) {
            float w = Wl[0][k * 64 + c];
#pragma unroll
            for (int i = 0; i < 16; ++i) acc[i] += xt[(g * 16 + i) * 64 + k] * w;
        }
#pragma unroll
        for (int i = 0; i < 16; ++i) {
            int gr = row0 + g * 16 + i;
            if (gr < N) qq[(size_t)gr * CH + c] = acc[i];
        }
    }
}

// ---------------------------------------------------------------------------
// Fused edge kernel: pos-MLP -> attn-MLP -> exp -> atomic scatter (num, den)
// One wave per edge, lane = channel. No segment-max needed (alpha bounded).
// ---------------------------------------------------------------------------
__global__ __launch_bounds__(256) void k_edge(
    const int* __restrict__ srcA, const int* __restrict__ dstA,
    const float* __restrict__ pos,
    const float* __restrict__ vv, const float* __restrict__ kk, const float* __restrict__ qq,
    const float* __restrict__ P1, const float* __restrict__ pb1,
    const float* __restrict__ P2, const float* __restrict__ pb2,
    const float* __restrict__ A1, const float* __restrict__ ab1,
    const float* __restrict__ A2, const float* __restrict__ ab2,
    float* __restrict__ num, float* __restrict__ den,
    int E, int Etot)
{
    __shared__ float P1s[3 * 64];
    __shared__ float P2s[64 * 64];
    __shared__ float A1s[64 * 64];
    __shared__ float A2s[64 * 64];
    __shared__ float wb[4][64];

    const int t = threadIdx.x;
    for (int i = t; i < 64 * 64; i += 256) {
        P2s[i] = P2[i];
        A1s[i] = A1[i];
        A2s[i] = A2[i];
        if (i < 3 * 64) P1s[i] = P1[i];
    }
    __syncthreads();

    const int lane = t & 63, wid = t >> 6;
    const float bp1 = pb1[lane], bp2 = pb2[lane], ba1 = ab1[lane], ba2 = ab2[lane];
    float* wbuf = wb[wid];

    const int wstart = blockIdx.x * 4 + wid;
    const int wstep = gridDim.x * 4;

    for (int e = wstart; e < Etot; e += wstep) {
        int s, d;
        if (e < E) { s = srcA[e]; d = dstA[e]; }
        else       { s = d = e - E; }

        float dx = pos[d * 3 + 0] - pos[s * 3 + 0];
        float dy = pos[d * 3 + 1] - pos[s * 3 + 1];
        float dz = pos[d * 3 + 2] - pos[s * 3 + 2];

        // pos MLP layer 1 (3 -> 64)
        float t1 = silu_f(dx * P1s[lane] + dy * P1s[64 + lane] + dz * P1s[128 + lane] + bp1);
        wbuf[lane] = t1;

        // pos MLP layer 2 (64 -> 64)
        float a0 = bp2, a1 = 0.0f, a2 = 0.0f, a3 = 0.0f;
#pragma unroll
        for (int k4 = 0; k4 < 16; ++k4) {
            float4 w = *(const float4*)&wbuf[k4 * 4];
            a0 += w.x * P2s[(k4 * 4 + 0) * 64 + lane];
            a1 += w.y * P2s[(k4 * 4 + 1) * 64 + lane];
            a2 += w.z * P2s[(k4 * 4 + 2) * 64 + lane];
            a3 += w.w * P2s[(k4 * 4 + 3) * 64 + lane];
        }
        float delta = silu_f((a0 + a1) + (a2 + a3));

        float msg = vv[s * CH + lane] + delta;
        float al0 = qq[d * CH + lane] - kk[s * CH + lane] + delta;

        // attn MLP layer 1
        wbuf[lane] = al0;
        a0 = ba1; a1 = 0.0f; a2 = 0.0f; a3 = 0.0f;
#pragma unroll
        for (int k4 = 0; k4 < 16; ++k4) {
            float4 w = *(const float4*)&wbuf[k4 * 4];
            a0 += w.x * A1s[(k4 * 4 + 0) * 64 + lane];
            a1 += w.y * A1s[(k4 * 4 + 1) * 64 + lane];
            a2 += w.z * A1s[(k4 * 4 + 2) * 64 + lane];
            a3 += w.w * A1s[(k4 * 4 + 3) * 64 + lane];
        }
        float y = silu_f((a0 + a1) + (a2 + a3));

        // attn MLP layer 2
        wbuf[lane] = y;
        a0 = ba2; a1 = 0.0f; a2 = 0.0f; a3 = 0.0f;
#pragma unroll
        for (int k4 = 0; k4 < 16; ++k4) {
            float4 w = *(const float4*)&wbuf[k4 * 4];
            a0 += w.x * A2s[(k4 * 4 + 0) * 64 + lane];
            a1 += w.y * A2s[(k4 * 4 + 1) * 64 + lane];
            a2 += w.z * A2s[(k4 * 4 + 2) * 64 + lane];
            a3 += w.w * A2s[(k4 * 4 + 3) * 64 + lane];
        }
        float alpha = silu_f((a0 + a1) + (a2 + a3));

        float ex = __expf(alpha);  // softmax shift-invariant; alpha bounded, safe
        atomicAdd(&den[d * CH + lane], ex);
        atomicAdd(&num[d * CH + lane], ex * msg);
    }
}

// ---------------------------------------------------------------------------
// Kernel: pre = num/den; o = pre @ Wout + bout ; accumulate BN2 stats
// ---------------------------------------------------------------------------
__global__ __launch_bounds__(256) void k_out(
    const float* __restrict__ num, const float* __restrict__ den,
    const float* __restrict__ Wout, const float* __restrict__ bout,
    float* __restrict__ o, float* __restrict__ ssum, float* __restrict__ ssq, int N)
{
    __shared__ float xt[64 * 64];
    __shared__ float Wl[64 * 64];
    __shared__ float red[2][4][64];
    const int t = threadIdx.x, c = t & 63, g = t >> 6;
    const int row0 = blockIdx.x * 64;

    for (int i = t; i < 64 * 64; i += 256) {
        int r = i >> 6, cc = i & 63;
        int gr = row0 + r;
        xt[i] = (gr < N) ? num[(size_t)gr * CH + cc] / den[(size_t)gr * CH + cc] : 0.0f;
        Wl[i] = Wout[i];
    }
    __syncthreads();

    float acc[16];
    const float b = bout[c];
#pragma unroll
    for (int i = 0; i < 16; ++i) acc[i] = b;
    for (int k = 0; k < 64; ++k) {
        float w = Wl[k * 64 + c];
#pragma unroll
        for (int i = 0; i < 16; ++i) acc[i] += xt[(g * 16 + i) * 64 + k] * w;
    }
    float s = 0.0f, ss = 0.0f;
#pragma unroll
    for (int i = 0; i < 16; ++i) {
        int gr = row0 + g * 16 + i;
        if (gr < N) {
            o[(size_t)gr * CH + c] = acc[i];
            s += acc[i];
            ss += acc[i] * acc[i];
        }
    }
    red[0][g][c] = s;
    red[1][g][c] = ss;
    __syncthreads();
    if (g == 0) {
        atomicAdd(&ssum[c], red[0][0][c] + red[0][1][c] + red[0][2][c] + red[0][3][c]);
        atomicAdd(&ssq[c],  red[1][0][c] + red[1][1][c] + red[1][2][c] + red[1][3][c]);
    }
}

// ---------------------------------------------------------------------------
// Kernel: out = o*scale2 + shift2
// ---------------------------------------------------------------------------
__global__ void k_final(const float* __restrict__ o, const float* __restrict__ scale,
                        const float* __restrict__ shift, float* __restrict__ out, int total)
{
    int i = blockIdx.x * blockDim.x + threadIdx.x;
    if (i < total) {
        int c = i & 63;
        out[i] = o[i] * scale[c] + shift[c];
    }
}

// ---------------------------------------------------------------------------
extern "C" void kernel_launch(void* const* d_in, const int* in_sizes, int n_in,
                              void* d_out, int out_size, void* d_ws, size_t ws_size,
                              hipStream_t stream)
{
    const float* x      = (const float*)d_in[0];
    const float* pos    = (const float*)d_in[1];
    const int*   ei     = (const int*)d_in[2];
    const float* Win    = (const float*)d_in[3];
    const float* bin    = (const float*)d_in[4];
    const float* gin    = (const float*)d_in[5];
    const float* betain = (const float*)d_in[6];
    const float* Wv     = (const float*)d_in[7];
    const float* Wk     = (const float*)d_in[8];
    const float* Wq     = (const float*)d_in[9];
    const float* P1     = (const float*)d_in[10];
    const float* pb1    = (const float*)d_in[11];
    const float* P2     = (const float*)d_in[12];
    const float* pb2    = (const float*)d_in[13];
    const float* A1     = (const float*)d_in[14];
    const float* ab1    = (const float*)d_in[15];
    const float* A2     = (const float*)d_in[16];
    const float* ab2    = (const float*)d_in[17];
    const float* Wout   = (const float*)d_in[18];
    const float* bout   = (const float*)d_in[19];
    const float* gout   = (const float*)d_in[20];
    const float* betaout= (const float*)d_in[21];

    const int N = in_sizes[0] / CH;
    const int E = in_sizes[2] / 2;
    const int Etot = E + N;
    const int* srcA = ei;
    const int* dstA = ei + E;

    float* ws = (float*)d_ws;
    const size_t NC = (size_t)N * CH;
    float* h   = ws;            // N*C   (reused as o after edge pass)
    float* vv  = h + NC;        // N*C
    float* kk  = vv + NC;       // N*C
    float* qq  = kk + NC;       // N*C
    float* num = qq + NC;       // N*C
    float* den = num + NC;      // N*C
    float* st  = den + NC;      // 512 floats of stats

    // zero num, den, stats in one shot (they are contiguous)
    hipMemsetAsync(num, 0, (2 * NC + 512) * sizeof(float), stream);

    const int nb = (N + 63) / 64;
    k_lin_in<<<nb, 256, 0, stream>>>(x, Win, bin, h, st, st + 64, N);
    k_stats<<<1, 64, 0, stream>>>(st, st + 64, gin, betain, st + 128, st + 192, N);
    k_vkq<<<nb, 256, 0, stream>>>(h, st + 128, st + 192, Wv, Wk, Wq, vv, kk, qq, N);
    k_edge<<<4096, 256, 0, stream>>>(srcA, dstA, pos, vv, kk, qq,
                                     P1, pb1, P2, pb2, A1, ab1, A2, ab2,
                                     num, den, E, Etot);
    k_out<<<nb, 256, 0, stream>>>(num, den, Wout, bout, h, st + 256, st + 320, N);
    k_stats<<<1, 64, 0, stream>>>(st + 256, st + 320, gout, betaout, st + 384, st + 448, N);
    k_final<<<(int)((NC + 255) / 256), 256, 0, stream>>>(h, st + 384, st + 448,
                                                         (float*)d_out, (int)NC);
}

// Round 2
// 524.695 us; speedup vs baseline: 1.7559x; 1.7559x over previous
//
#include <hip/hip_runtime.h>

#define CH 64
#define BN_EPS 1e-5f

typedef __attribute__((ext_vector_type(8))) __bf16 bf16x8;
typedef __attribute__((ext_vector_type(4))) float f32x4;

__device__ __forceinline__ float silu_f(float x) { return x / (1.0f + __expf(-x)); }

// ---------------------------------------------------------------------------
// Kernel: h = x @ Win + bin ; accumulate per-channel sum/sumsq for BN1
// ---------------------------------------------------------------------------
__global__ __launch_bounds__(256) void k_lin_in(
    const float* __restrict__ x, const float* __restrict__ Win, const float* __restrict__ bin,
    float* __restrict__ h, float* __restrict__ ssum, float* __restrict__ ssq, int N)
{
    __shared__ float xt[64 * 64];
    __shared__ float Wl[64 * 64];
    __shared__ float red[2][4][64];
    const int t = threadIdx.x, c = t & 63, g = t >> 6;
    const int row0 = blockIdx.x * 64;

    for (int i = t; i < 64 * 64; i += 256) {
        int r = i >> 6, cc = i & 63;
        int gr = row0 + r;
        xt[i] = (gr < N) ? x[(size_t)gr * CH + cc] : 0.0f;
        Wl[i] = Win[i];
    }
    __syncthreads();

    float acc[16];
    const float b = bin[c];
#pragma unroll
    for (int i = 0; i < 16; ++i) acc[i] = b;
    for (int k = 0; k < 64; ++k) {
        float w = Wl[k * 64 + c];
#pragma unroll
        for (int i = 0; i < 16; ++i) acc[i] += xt[(g * 16 + i) * 64 + k] * w;
    }
    float s = 0.0f, ss = 0.0f;
#pragma unroll
    for (int i = 0; i < 16; ++i) {
        int gr = row0 + g * 16 + i;
        if (gr < N) {
            h[(size_t)gr * CH + c] = acc[i];
            s += acc[i];
            ss += acc[i] * acc[i];
        }
    }
    red[0][g][c] = s;
    red[1][g][c] = ss;
    __syncthreads();
    if (g == 0) {
        atomicAdd(&ssum[c], red[0][0][c] + red[0][1][c] + red[0][2][c] + red[0][3][c]);
        atomicAdd(&ssq[c],  red[1][0][c] + red[1][1][c] + red[1][2][c] + red[1][3][c]);
    }
}

// ---------------------------------------------------------------------------
__global__ void k_stats(const float* __restrict__ ssum, const float* __restrict__ ssq,
                        const float* __restrict__ gamma, const float* __restrict__ beta,
                        float* __restrict__ scale, float* __restrict__ shift, int N)
{
    int c = threadIdx.x;
    float inv = 1.0f / (float)N;
    float mu = ssum[c] * inv;
    float var = ssq[c] * inv - mu * mu;
    float sc = gamma[c] * rsqrtf(var + BN_EPS);
    scale[c] = sc;
    shift[c] = beta[c] - mu * sc;
}

// ---------------------------------------------------------------------------
// Kernel: x1 = silu(h*scale+shift); v = x1@Wv; k = x1@Wk; q = x1@Wq
// ---------------------------------------------------------------------------
__global__ __launch_bounds__(256) void k_vkq(
    const float* __restrict__ h, const float* __restrict__ scale, const float* __restrict__ shift,
    const float* __restrict__ Wv, const float* __restrict__ Wk, const float* __restrict__ Wq,
    float* __restrict__ vv, float* __restrict__ kk, float* __restrict__ qq, int N)
{
    __shared__ float xt[64 * 64];
    __shared__ float Wl[2][64 * 64];
    const int t = threadIdx.x, c = t & 63, g = t >> 6;
    const int row0 = blockIdx.x * 64;

    for (int i = t; i < 64 * 64; i += 256) {
        int r = i >> 6, cc = i & 63;
        int gr = row0 + r;
        float hv = (gr < N) ? h[(size_t)gr * CH + cc] : 0.0f;
        xt[i] = silu_f(hv * scale[cc] + shift[cc]);
        Wl[0][i] = Wv[i];
        Wl[1][i] = Wk[i];
    }
    __syncthreads();

    for (int m = 0; m < 2; ++m) {
        float acc[16];
#pragma unroll
        for (int i = 0; i < 16; ++i) acc[i] = 0.0f;
        for (int k = 0; k < 64; ++k) {
            float w = Wl[m][k * 64 + c];
#pragma unroll
            for (int i = 0; i < 16; ++i) acc[i] += xt[(g * 16 + i) * 64 + k] * w;
        }
        float* o = (m == 0) ? vv : kk;
#pragma unroll
        for (int i = 0; i < 16; ++i) {
            int gr = row0 + g * 16 + i;
            if (gr < N) o[(size_t)gr * CH + c] = acc[i];
        }
    }
    __syncthreads();
    for (int i = t; i < 64 * 64; i += 256) Wl[0][i] = Wq[i];
    __syncthreads();
    {
        float acc[16];
#pragma unroll
        for (int i = 0; i < 16; ++i) acc[i] = 0.0f;
        for (int k = 0; k < 64; ++k) {
            float w = Wl[0][k * 64 + c];
#pragma unroll
            for (int i = 0; i < 16; ++i) acc[i] += xt[(g * 16 + i) * 64 + k] * w;
        }
#pragma unroll
        for (int i = 0; i < 16; ++i) {
            int gr = row0 + g * 16 + i;
            if (gr < N) qq[(size_t)gr * CH + c] = acc[i];
        }
    }
}

// ---------------------------------------------------------------------------
// MFMA edge kernel. One wave handles 16 edges per iteration.
//  - 16x16x32 bf16 MFMA; M=edges(16), N=co(4 tiles of 16), K=64 (2 k-steps)
//  - pos layer (K=3) zero-padded into one k-step (4 MFMAs)
//  - B-fragments of P2/A1/A2 pre-packed in LDS, 1 ds_read_b128 per fragment
//  - inter-layer transpose (D-layout -> A-layout) via per-wave LDS buffer
//  - A and B frags use the same nominal lane->k map, so the contraction is
//    correct regardless of the true intra-k permutation; only the C/D map
//    (col=lane&15, row=(lane>>4)*4+reg, verified m89) is load-bearing.
// ---------------------------------------------------------------------------
__global__ __launch_bounds__(256) void k_edge_mfma(
    const int* __restrict__ srcA, const int* __restrict__ dstA,
    const float* __restrict__ pos,
    const float* __restrict__ vv, const float* __restrict__ kk, const float* __restrict__ qq,
    const float* __restrict__ P1, const float* __restrict__ pb1,
    const float* __restrict__ P2, const float* __restrict__ pb2,
    const float* __restrict__ A1, const float* __restrict__ ab1,
    const float* __restrict__ A2, const float* __restrict__ ab2,
    float* __restrict__ num, float* __restrict__ den,
    int E, int Etot, int nChunks)
{
    __shared__ __align__(16) __bf16 Wtab[3][8][64][8];   // [mat][nt*2+ks][lane][j]
    __shared__ __align__(16) float tbuf[4][16 * 68];     // per-wave transpose buffer

    const int t = threadIdx.x;
    // Pack B-fragment tables: frag elem j of lane l for (nt,ks) is W[k][n],
    // k = ks*32 + (l>>4)*8 + j, n = nt*16 + (l&15).
    for (int i = t; i < 3 * 4096; i += 256) {
        int mat = i >> 12, r = i & 4095;
        int j = r & 7, lane = (r >> 3) & 63, ksnt = r >> 9;
        int ks = ksnt & 1, nt = ksnt >> 1;
        int k = ks * 32 + ((lane >> 4) & 3) * 8 + j;
        int n = nt * 16 + (lane & 15);
        const float* W = (mat == 0) ? P2 : ((mat == 1) ? A1 : A2);
        Wtab[mat][ksnt][lane][j] = (__bf16)W[k * 64 + n];
    }
    __syncthreads();

    const int l = t & 63, wid = t >> 6;
    const int lg = l >> 4, lm = l & 15;
    float* buf = tbuf[wid];

    float pb1r[4], pb2r[4], ab1r[4], ab2r[4];
    bf16x8 p1f[4];
#pragma unroll
    for (int nt = 0; nt < 4; ++nt) {
        int co = nt * 16 + lm;
        pb1r[nt] = pb1[co]; pb2r[nt] = pb2[co];
        ab1r[nt] = ab1[co]; ab2r[nt] = ab2[co];
        bf16x8 f;
#pragma unroll
        for (int j = 0; j < 8; ++j)
            f[j] = (__bf16)((lg == 0 && j < 3) ? P1[j * 64 + co] : 0.0f);
        p1f[nt] = f;
    }

    for (int ch = blockIdx.x; ch < nChunks; ch += gridDim.x) {
        const int e0 = ch * 64 + wid * 16;
        const int eA = e0 + lm;
        int sA = 0, dA = 0;
        const bool vAv = (eA < Etot);
        if (vAv) {
            if (eA < E) { sA = srcA[eA]; dA = dstA[eA]; }
            else        { sA = dA = eA - E; }
        }

        // ---- layer P1 (K=3, zero padded), A-frag nonzero only on lanes 0-15
        float pdx = 0.0f, pdy = 0.0f, pdz = 0.0f;
        if (lg == 0 && vAv) {
            pdx = pos[dA * 3 + 0] - pos[sA * 3 + 0];
            pdy = pos[dA * 3 + 1] - pos[sA * 3 + 1];
            pdz = pos[dA * 3 + 2] - pos[sA * 3 + 2];
        }
        bf16x8 af;
        af[0] = (__bf16)pdx; af[1] = (__bf16)pdy; af[2] = (__bf16)pdz;
        af[3] = af[4] = af[5] = af[6] = af[7] = (__bf16)0.0f;

        f32x4 acc[4];
#pragma unroll
        for (int nt = 0; nt < 4; ++nt) {
            f32x4 a; a[0] = a[1] = a[2] = a[3] = pb1r[nt];
            acc[nt] = __builtin_amdgcn_mfma_f32_16x16x32_bf16(af, p1f[nt], a, 0, 0, 0);
        }
        // t1 = silu -> LDS (D-layout write)
#pragma unroll
        for (int nt = 0; nt < 4; ++nt)
#pragma unroll
            for (int jj = 0; jj < 4; ++jj)
                buf[(lg * 4 + jj) * 68 + nt * 16 + lm] = silu_f(acc[nt][jj]);

        // A-frag read of t1: row = lm (edge), k = lg*8.. (+32 for k-step 1)
        const float* rp = &buf[lm * 68 + lg * 8];
        float4 x0 = *(const float4*)(rp);
        float4 x1 = *(const float4*)(rp + 4);
        float4 x2 = *(const float4*)(rp + 32);
        float4 x3 = *(const float4*)(rp + 36);
        bf16x8 aX0, aX1;
        aX0[0]=(__bf16)x0.x; aX0[1]=(__bf16)x0.y; aX0[2]=(__bf16)x0.z; aX0[3]=(__bf16)x0.w;
        aX0[4]=(__bf16)x1.x; aX0[5]=(__bf16)x1.y; aX0[6]=(__bf16)x1.z; aX0[7]=(__bf16)x1.w;
        aX1[0]=(__bf16)x2.x; aX1[1]=(__bf16)x2.y; aX1[2]=(__bf16)x2.z; aX1[3]=(__bf16)x2.w;
        aX1[4]=(__bf16)x3.x; aX1[5]=(__bf16)x3.y; aX1[6]=(__bf16)x3.z; aX1[7]=(__bf16)x3.w;

        // ---- layer P2
#pragma unroll
        for (int nt = 0; nt < 4; ++nt) {
            f32x4 a; a[0] = a[1] = a[2] = a[3] = pb2r[nt];
            bf16x8 b0 = *(const bf16x8*)&Wtab[0][nt * 2 + 0][l][0];
            bf16x8 b1 = *(const bf16x8*)&Wtab[0][nt * 2 + 1][l][0];
            a = __builtin_amdgcn_mfma_f32_16x16x32_bf16(aX0, b0, a, 0, 0, 0);
            a = __builtin_amdgcn_mfma_f32_16x16x32_bf16(aX1, b1, a, 0, 0, 0);
            acc[nt] = a;
        }
        // delta: keep in regs (D-layout, for msg) and write to LDS (for A-frag)
        float dlt[4][4];
#pragma unroll
        for (int nt = 0; nt < 4; ++nt)
#pragma unroll
            for (int jj = 0; jj < 4; ++jj) {
                float dv = silu_f(acc[nt][jj]);
                dlt[nt][jj] = dv;
                buf[(lg * 4 + jj) * 68 + nt * 16 + lm] = dv;
            }

        // ---- gather q[dA], k[sA] in A-layout (16 floats each)
        const float* qp = qq + (size_t)dA * 64 + lg * 8;
        const float* kp = kk + (size_t)sA * 64 + lg * 8;
        float4 q0 = *(const float4*)(qp);      float4 q1 = *(const float4*)(qp + 4);
        float4 q2 = *(const float4*)(qp + 32); float4 q3 = *(const float4*)(qp + 36);
        float4 k0 = *(const float4*)(kp);      float4 k1 = *(const float4*)(kp + 4);
        float4 k2 = *(const float4*)(kp + 32); float4 k3 = *(const float4*)(kp + 36);
        float4 d0 = *(const float4*)(rp);
        float4 d1 = *(const float4*)(rp + 4);
        float4 d2 = *(const float4*)(rp + 32);
        float4 d3 = *(const float4*)(rp + 36);

        bf16x8 aA0, aA1;
        aA0[0]=(__bf16)(q0.x-k0.x+d0.x); aA0[1]=(__bf16)(q0.y-k0.y+d0.y);
        aA0[2]=(__bf16)(q0.z-k0.z+d0.z); aA0[3]=(__bf16)(q0.w-k0.w+d0.w);
        aA0[4]=(__bf16)(q1.x-k1.x+d1.x); aA0[5]=(__bf16)(q1.y-k1.y+d1.y);
        aA0[6]=(__bf16)(q1.z-k1.z+d1.z); aA0[7]=(__bf16)(q1.w-k1.w+d1.w);
        aA1[0]=(__bf16)(q2.x-k2.x+d2.x); aA1[1]=(__bf16)(q2.y-k2.y+d2.y);
        aA1[2]=(__bf16)(q2.z-k2.z+d2.z); aA1[3]=(__bf16)(q2.w-k2.w+d2.w);
        aA1[4]=(__bf16)(q3.x-k3.x+d3.x); aA1[5]=(__bf16)(q3.y-k3.y+d3.y);
        aA1[6]=(__bf16)(q3.z-k3.z+d3.z); aA1[7]=(__bf16)(q3.w-k3.w+d3.w);

        // ---- layer A1
#pragma unroll
        for (int nt = 0; nt < 4; ++nt) {
            f32x4 a; a[0] = a[1] = a[2] = a[3] = ab1r[nt];
            bf16x8 b0 = *(const bf16x8*)&Wtab[1][nt * 2 + 0][l][0];
            bf16x8 b1 = *(const bf16x8*)&Wtab[1][nt * 2 + 1][l][0];
            a = __builtin_amdgcn_mfma_f32_16x16x32_bf16(aA0, b0, a, 0, 0, 0);
            a = __builtin_amdgcn_mfma_f32_16x16x32_bf16(aA1, b1, a, 0, 0, 0);
            acc[nt] = a;
        }
        // y = silu -> LDS -> A-frag
#pragma unroll
        for (int nt = 0; nt < 4; ++nt)
#pragma unroll
            for (int jj = 0; jj < 4; ++jj)
                buf[(lg * 4 + jj) * 68 + nt * 16 + lm] = silu_f(acc[nt][jj]);

        float4 y0 = *(const float4*)(rp);
        float4 y1 = *(const float4*)(rp + 4);
        float4 y2 = *(const float4*)(rp + 32);
        float4 y3 = *(const float4*)(rp + 36);
        bf16x8 aY0, aY1;
        aY0[0]=(__bf16)y0.x; aY0[1]=(__bf16)y0.y; aY0[2]=(__bf16)y0.z; aY0[3]=(__bf16)y0.w;
        aY0[4]=(__bf16)y1.x; aY0[5]=(__bf16)y1.y; aY0[6]=(__bf16)y1.z; aY0[7]=(__bf16)y1.w;
        aY1[0]=(__bf16)y2.x; aY1[1]=(__bf16)y2.y; aY1[2]=(__bf16)y2.z; aY1[3]=(__bf16)y2.w;
        aY1[4]=(__bf16)y3.x; aY1[5]=(__bf16)y3.y; aY1[6]=(__bf16)y3.z; aY1[7]=(__bf16)y3.w;

        // ---- layer A2
#pragma unroll
        for (int nt = 0; nt < 4; ++nt) {
            f32x4 a; a[0] = a[1] = a[2] = a[3] = ab2r[nt];
            bf16x8 b0 = *(const bf16x8*)&Wtab[2][nt * 2 + 0][l][0];
            bf16x8 b1 = *(const bf16x8*)&Wtab[2][nt * 2 + 1][l][0];
            a = __builtin_amdgcn_mfma_f32_16x16x32_bf16(aA0 /*dummy init*/, b0, a, 0, 0, 0);
            // NOTE: the line above is replaced below; kept structure simple
            a[0] = a[1] = a[2] = a[3] = ab2r[nt];
            a = __builtin_amdgcn_mfma_f32_16x16x32_bf16(aY0, b0, a, 0, 0, 0);
            a = __builtin_amdgcn_mfma_f32_16x16x32_bf16(aY1, b1, a, 0, 0, 0);
            acc[nt] = a;
        }

        // alpha = silu, ex = exp(alpha)
        float exv[4][4];
#pragma unroll
        for (int nt = 0; nt < 4; ++nt)
#pragma unroll
            for (int jj = 0; jj < 4; ++jj)
                exv[nt][jj] = __expf(silu_f(acc[nt][jj]));

        // ---- scatter: lane covers co = nt*16+lm for edge er = lg*4+jj
#pragma unroll
        for (int jj = 0; jj < 4; ++jj) {
            const int er = lg * 4 + jj;
            const int eD = e0 + er;
            const bool vD = (eD < Etot);
            const int sD = __shfl(sA, er);
            const int dD = __shfl(dA, er);
            if (vD) {
                const size_t vb = (size_t)sD * 64 + lm;
                const size_t ob = (size_t)dD * 64 + lm;
#pragma unroll
                for (int nt = 0; nt < 4; ++nt) {
                    float vval = vv[vb + nt * 16];
                    float e = exv[nt][jj];
                    atomicAdd(&den[ob + nt * 16], e);
                    atomicAdd(&num[ob + nt * 16], e * (vval + dlt[nt][jj]));
                }
            }
        }
    }
}

// ---------------------------------------------------------------------------
// Kernel: pre = num/den; o = pre @ Wout + bout ; accumulate BN2 stats
// ---------------------------------------------------------------------------
__global__ __launch_bounds__(256) void k_out(
    const float* __restrict__ num, const float* __restrict__ den,
    const float* __restrict__ Wout, const float* __restrict__ bout,
    float* __restrict__ o, float* __restrict__ ssum, float* __restrict__ ssq, int N)
{
    __shared__ float xt[64 * 64];
    __shared__ float Wl[64 * 64];
    __shared__ float red[2][4][64];
    const int t = threadIdx.x, c = t & 63, g = t >> 6;
    const int row0 = blockIdx.x * 64;

    for (int i = t; i < 64 * 64; i += 256) {
        int r = i >> 6, cc = i & 63;
        int gr = row0 + r;
        xt[i] = (gr < N) ? num[(size_t)gr * CH + cc] / den[(size_t)gr * CH + cc] : 0.0f;
        Wl[i] = Wout[i];
    }
    __syncthreads();

    float acc[16];
    const float b = bout[c];
#pragma unroll
    for (int i = 0; i < 16; ++i) acc[i] = b;
    for (int k = 0; k < 64; ++k) {
        float w = Wl[k * 64 + c];
#pragma unroll
        for (int i = 0; i < 16; ++i) acc[i] += xt[(g * 16 + i) * 64 + k] * w;
    }
    float s = 0.0f, ss = 0.0f;
#pragma unroll
    for (int i = 0; i < 16; ++i) {
        int gr = row0 + g * 16 + i;
        if (gr < N) {
            o[(size_t)gr * CH + c] = acc[i];
            s += acc[i];
            ss += acc[i] * acc[i];
        }
    }
    red[0][g][c] = s;
    red[1][g][c] = ss;
    __syncthreads();
    if (g == 0) {
        atomicAdd(&ssum[c], red[0][0][c] + red[0][1][c] + red[0][2][c] + red[0][3][c]);
        atomicAdd(&ssq[c],  red[1][0][c] + red[1][1][c] + red[1][2][c] + red[1][3][c]);
    }
}

// ---------------------------------------------------------------------------
__global__ void k_final(const float* __restrict__ o, const float* __restrict__ scale,
                        const float* __restrict__ shift, float* __restrict__ out, int total)
{
    int i = blockIdx.x * blockDim.x + threadIdx.x;
    if (i < total) {
        int c = i & 63;
        out[i] = o[i] * scale[c] + shift[c];
    }
}

// ---------------------------------------------------------------------------
extern "C" void kernel_launch(void* const* d_in, const int* in_sizes, int n_in,
                              void* d_out, int out_size, void* d_ws, size_t ws_size,
                              hipStream_t stream)
{
    const float* x      = (const float*)d_in[0];
    const float* pos    = (const float*)d_in[1];
    const int*   ei     = (const int*)d_in[2];
    const float* Win    = (const float*)d_in[3];
    const float* bin    = (const float*)d_in[4];
    const float* gin    = (const float*)d_in[5];
    const float* betain = (const float*)d_in[6];
    const float* Wv     = (const float*)d_in[7];
    const float* Wk     = (const float*)d_in[8];
    const float* Wq     = (const float*)d_in[9];
    const float* P1     = (const float*)d_in[10];
    const float* pb1    = (const float*)d_in[11];
    const float* P2     = (const float*)d_in[12];
    const float* pb2    = (const float*)d_in[13];
    const float* A1     = (const float*)d_in[14];
    const float* ab1    = (const float*)d_in[15];
    const float* A2     = (const float*)d_in[16];
    const float* ab2    = (const float*)d_in[17];
    const float* Wout   = (const float*)d_in[18];
    const float* bout   = (const float*)d_in[19];
    const float* gout   = (const float*)d_in[20];
    const float* betaout= (const float*)d_in[21];

    const int N = in_sizes[0] / CH;
    const int E = in_sizes[2] / 2;
    const int Etot = E + N;
    const int* srcA = ei;
    const int* dstA = ei + E;

    float* ws = (float*)d_ws;
    const size_t NC = (size_t)N * CH;
    float* h   = ws;            // N*C   (reused as o after edge pass)
    float* vv  = h + NC;        // N*C
    float* kk  = vv + NC;       // N*C
    float* qq  = kk + NC;       // N*C
    float* num = qq + NC;       // N*C
    float* den = num + NC;      // N*C
    float* st  = den + NC;      // 512 floats of stats

    hipMemsetAsync(num, 0, (2 * NC + 512) * sizeof(float), stream);

    const int nb = (N + 63) / 64;
    k_lin_in<<<nb, 256, 0, stream>>>(x, Win, bin, h, st, st + 64, N);
    k_stats<<<1, 64, 0, stream>>>(st, st + 64, gin, betain, st + 128, st + 192, N);
    k_vkq<<<nb, 256, 0, stream>>>(h, st + 128, st + 192, Wv, Wk, Wq, vv, kk, qq, N);

    const int nChunks = (Etot + 63) / 64;
    const int grid = (nChunks < 2048) ? nChunks : 2048;
    k_edge_mfma<<<grid, 256, 0, stream>>>(srcA, dstA, pos, vv, kk, qq,
                                          P1, pb1, P2, pb2, A1, ab1, A2, ab2,
                                          num, den, E, Etot, nChunks);

    k_out<<<nb, 256, 0, stream>>>(num, den, Wout, bout, h, st + 256, st + 320, N);
    k_stats<<<1, 64, 0, stream>>>(st + 256, st + 320, gout, betaout, st + 384, st + 448, N);
    k_final<<<(int)((NC + 255) / 256), 256, 0, stream>>>(h, st + 384, st + 448,
                                                         (float*)d_out, (int)NC);
}

// Round 3
// 513.539 us; speedup vs baseline: 1.7940x; 1.0217x over previous
//
#include <hip/hip_runtime.h>

#define CH 64
#define BN_EPS 1e-5f

typedef __attribute__((ext_vector_type(8))) __bf16 bf16x8;
typedef __attribute__((ext_vector_type(4))) float f32x4;

__device__ __forceinline__ float silu_f(float x) { return x / (1.0f + __expf(-x)); }

// ---------------------------------------------------------------------------
// Kernel: h = x @ Win + bin ; accumulate per-channel sum/sumsq for BN1
// ---------------------------------------------------------------------------
__global__ __launch_bounds__(256) void k_lin_in(
    const float* __restrict__ x, const float* __restrict__ Win, const float* __restrict__ bin,
    float* __restrict__ h, float* __restrict__ ssum, float* __restrict__ ssq, int N)
{
    __shared__ float xt[64 * 64];
    __shared__ float Wl[64 * 64];
    __shared__ float red[2][4][64];
    const int t = threadIdx.x, c = t & 63, g = t >> 6;
    const int row0 = blockIdx.x * 64;

    for (int i = t; i < 64 * 64; i += 256) {
        int r = i >> 6, cc = i & 63;
        int gr = row0 + r;
        xt[i] = (gr < N) ? x[(size_t)gr * CH + cc] : 0.0f;
        Wl[i] = Win[i];
    }
    __syncthreads();

    float acc[16];
    const float b = bin[c];
#pragma unroll
    for (int i = 0; i < 16; ++i) acc[i] = b;
    for (int k = 0; k < 64; ++k) {
        float w = Wl[k * 64 + c];
#pragma unroll
        for (int i = 0; i < 16; ++i) acc[i] += xt[(g * 16 + i) * 64 + k] * w;
    }
    float s = 0.0f, ss = 0.0f;
#pragma unroll
    for (int i = 0; i < 16; ++i) {
        int gr = row0 + g * 16 + i;
        if (gr < N) {
            h[(size_t)gr * CH + c] = acc[i];
            s += acc[i];
            ss += acc[i] * acc[i];
        }
    }
    red[0][g][c] = s;
    red[1][g][c] = ss;
    __syncthreads();
    if (g == 0) {
        atomicAdd(&ssum[c], red[0][0][c] + red[0][1][c] + red[0][2][c] + red[0][3][c]);
        atomicAdd(&ssq[c],  red[1][0][c] + red[1][1][c] + red[1][2][c] + red[1][3][c]);
    }
}

// ---------------------------------------------------------------------------
__global__ void k_stats(const float* __restrict__ ssum, const float* __restrict__ ssq,
                        const float* __restrict__ gamma, const float* __restrict__ beta,
                        float* __restrict__ scale, float* __restrict__ shift, int N)
{
    int c = threadIdx.x;
    float inv = 1.0f / (float)N;
    float mu = ssum[c] * inv;
    float var = ssq[c] * inv - mu * mu;
    float sc = gamma[c] * rsqrtf(var + BN_EPS);
    scale[c] = sc;
    shift[c] = beta[c] - mu * sc;
}

// ---------------------------------------------------------------------------
// Kernel: x1 = silu(h*scale+shift); v/k/q = x1@W — stored as bf16
// ---------------------------------------------------------------------------
__global__ __launch_bounds__(256) void k_vkq(
    const float* __restrict__ h, const float* __restrict__ scale, const float* __restrict__ shift,
    const float* __restrict__ Wv, const float* __restrict__ Wk, const float* __restrict__ Wq,
    __bf16* __restrict__ vv, __bf16* __restrict__ kk, __bf16* __restrict__ qq, int N)
{
    __shared__ float xt[64 * 64];
    __shared__ float Wl[2][64 * 64];
    const int t = threadIdx.x, c = t & 63, g = t >> 6;
    const int row0 = blockIdx.x * 64;

    for (int i = t; i < 64 * 64; i += 256) {
        int r = i >> 6, cc = i & 63;
        int gr = row0 + r;
        float hv = (gr < N) ? h[(size_t)gr * CH + cc] : 0.0f;
        xt[i] = silu_f(hv * scale[cc] + shift[cc]);
        Wl[0][i] = Wv[i];
        Wl[1][i] = Wk[i];
    }
    __syncthreads();

    for (int m = 0; m < 2; ++m) {
        float acc[16];
#pragma unroll
        for (int i = 0; i < 16; ++i) acc[i] = 0.0f;
        for (int k = 0; k < 64; ++k) {
            float w = Wl[m][k * 64 + c];
#pragma unroll
            for (int i = 0; i < 16; ++i) acc[i] += xt[(g * 16 + i) * 64 + k] * w;
        }
        __bf16* o = (m == 0) ? vv : kk;
#pragma unroll
        for (int i = 0; i < 16; ++i) {
            int gr = row0 + g * 16 + i;
            if (gr < N) o[(size_t)gr * CH + c] = (__bf16)acc[i];
        }
    }
    __syncthreads();
    for (int i = t; i < 64 * 64; i += 256) Wl[0][i] = Wq[i];
    __syncthreads();
    {
        float acc[16];
#pragma unroll
        for (int i = 0; i < 16; ++i) acc[i] = 0.0f;
        for (int k = 0; k < 64; ++k) {
            float w = Wl[0][k * 64 + c];
#pragma unroll
            for (int i = 0; i < 16; ++i) acc[i] += xt[(g * 16 + i) * 64 + k] * w;
        }
#pragma unroll
        for (int i = 0; i < 16; ++i) {
            int gr = row0 + g * 16 + i;
            if (gr < N) qq[(size_t)gr * CH + c] = (__bf16)acc[i];
        }
    }
}

// ---------------------------------------------------------------------------
// MFMA edge kernel, software-pipelined.
//  - 16 edges per wave-iteration, 16x16x32 bf16 MFMA
//  - cross-iteration prefetch: indices -> (pos-delta, q-k) one iter ahead
//  - v gathers issued at body top, consumed at scatter (full-body cover)
//  - bf16 transpose buffer [16][72], A-frags via single ds_read_b128
// ---------------------------------------------------------------------------
__global__ __launch_bounds__(256) void k_edge_mfma(
    const int* __restrict__ srcA, const int* __restrict__ dstA,
    const float* __restrict__ pos,
    const __bf16* __restrict__ vvb, const __bf16* __restrict__ kkb, const __bf16* __restrict__ qqb,
    const float* __restrict__ P1, const float* __restrict__ pb1,
    const float* __restrict__ P2, const float* __restrict__ pb2,
    const float* __restrict__ A1, const float* __restrict__ ab1,
    const float* __restrict__ A2, const float* __restrict__ ab2,
    float* __restrict__ num, float* __restrict__ den,
    int E, int Etot, int nChunks)
{
    __shared__ __align__(16) __bf16 Wtab[3][8][64][8];   // 24.0 KiB
    __shared__ __align__(16) __bf16 tb[4][16][72];       //  9.0 KiB

    const int t = threadIdx.x;
    // Pack B-fragment tables: elem j of lane l for (nt,ks) = W[k][n],
    // k = ks*32 + (l>>4)*8 + j, n = nt*16 + (l&15).
    for (int i = t; i < 3 * 4096; i += 256) {
        int mat = i >> 12, r = i & 4095;
        int j = r & 7, lane = (r >> 3) & 63, ksnt = r >> 9;
        int ks = ksnt & 1, nt = ksnt >> 1;
        int k = ks * 32 + ((lane >> 4) & 3) * 8 + j;
        int n = nt * 16 + (lane & 15);
        const float* W = (mat == 0) ? P2 : ((mat == 1) ? A1 : A2);
        Wtab[mat][ksnt][lane][j] = (__bf16)W[k * 64 + n];
    }
    __syncthreads();

    const int l = t & 63, wid = t >> 6, lg = l >> 4, lm = l & 15;
    __bf16* tbw = &tb[wid][0][0];

    float pb1r[4], pb2r[4], ab1r[4], ab2r[4];
    bf16x8 p1f[4];
#pragma unroll
    for (int nt = 0; nt < 4; ++nt) {
        int co = nt * 16 + lm;
        pb1r[nt] = pb1[co]; pb2r[nt] = pb2[co];
        ab1r[nt] = ab1[co]; ab2r[nt] = ab2[co];
        bf16x8 f;
#pragma unroll
        for (int j = 0; j < 8; ++j)
            f[j] = (__bf16)((lg == 0 && j < 3) ? P1[j * 64 + co] : 0.0f);
        p1f[nt] = f;
    }

    int ch = blockIdx.x;
    if (ch >= nChunks) return;

    // ---- pipeline prologue: indices + gathers for first chunk
    int sC = 0, dC = 0;
    {
        int eA = ch * 64 + wid * 16 + lm;
        if (eA < Etot) { if (eA < E) { sC = srcA[eA]; dC = dstA[eA]; } else { sC = dC = eA - E; } }
    }
    float pdl[3];
    bf16x8 qmk0, qmk1;
    {
        const float* ps = pos + (size_t)sC * 3;
        const float* pd = pos + (size_t)dC * 3;
        pdl[0] = pd[0] - ps[0]; pdl[1] = pd[1] - ps[1]; pdl[2] = pd[2] - ps[2];
        const __bf16* qp = qqb + (size_t)dC * 64 + lg * 8;
        const __bf16* kp = kkb + (size_t)sC * 64 + lg * 8;
        bf16x8 q0 = *(const bf16x8*)qp, q1 = *(const bf16x8*)(qp + 32);
        bf16x8 k0 = *(const bf16x8*)kp, k1 = *(const bf16x8*)(kp + 32);
#pragma unroll
        for (int j = 0; j < 8; ++j) {
            qmk0[j] = (__bf16)((float)q0[j] - (float)k0[j]);
            qmk1[j] = (__bf16)((float)q1[j] - (float)k1[j]);
        }
    }

    for (;;) {
        const int e0 = ch * 64 + wid * 16;
        const int chn = ch + gridDim.x;
        const bool hn = chn < nChunks;

        // ---- stage A: next chunk indices (issued early)
        int sN = 0, dN = 0;
        if (hn) {
            int eA = chn * 64 + wid * 16 + lm;
            if (eA < Etot) { if (eA < E) { sN = srcA[eA]; dN = dstA[eA]; } else { sN = dN = eA - E; } }
        }

        // ---- stage B: v gathers for current (consumed at scatter, end of body)
        int dD[4];
        __bf16 vpre[4][4];
#pragma unroll
        for (int jj = 0; jj < 4; ++jj) {
            int sD = __shfl(sC, lg * 4 + jj);
            dD[jj] = __shfl(dC, lg * 4 + jj);
            const __bf16* vp = vvb + (size_t)sD * 64 + lm;
#pragma unroll
            for (int nt = 0; nt < 4; ++nt) vpre[jj][nt] = vp[nt * 16];
        }

        // ---- P1 (K=3, zero-padded; only lane-group 0 carries data)
        bf16x8 af;
        af[0] = (lg == 0) ? (__bf16)pdl[0] : (__bf16)0.0f;
        af[1] = (lg == 0) ? (__bf16)pdl[1] : (__bf16)0.0f;
        af[2] = (lg == 0) ? (__bf16)pdl[2] : (__bf16)0.0f;
        af[3] = af[4] = af[5] = af[6] = af[7] = (__bf16)0.0f;
        f32x4 acc[4];
#pragma unroll
        for (int nt = 0; nt < 4; ++nt) {
            f32x4 a; a[0] = a[1] = a[2] = a[3] = pb1r[nt];
            acc[nt] = __builtin_amdgcn_mfma_f32_16x16x32_bf16(af, p1f[nt], a, 0, 0, 0);
        }
#pragma unroll
        for (int nt = 0; nt < 4; ++nt)
#pragma unroll
            for (int jj = 0; jj < 4; ++jj)
                tbw[(lg * 4 + jj) * 72 + nt * 16 + lm] = (__bf16)silu_f(acc[nt][jj]);
        bf16x8 aX0 = *(const bf16x8*)&tbw[lm * 72 + lg * 8];
        bf16x8 aX1 = *(const bf16x8*)&tbw[lm * 72 + 32 + lg * 8];

        // ---- P2
#pragma unroll
        for (int nt = 0; nt < 4; ++nt) {
            f32x4 a; a[0] = a[1] = a[2] = a[3] = pb2r[nt];
            a = __builtin_amdgcn_mfma_f32_16x16x32_bf16(aX0, *(const bf16x8*)&Wtab[0][nt * 2 + 0][l][0], a, 0, 0, 0);
            a = __builtin_amdgcn_mfma_f32_16x16x32_bf16(aX1, *(const bf16x8*)&Wtab[0][nt * 2 + 1][l][0], a, 0, 0, 0);
            acc[nt] = a;
        }
        float dlt[4][4];
#pragma unroll
        for (int nt = 0; nt < 4; ++nt)
#pragma unroll
            for (int jj = 0; jj < 4; ++jj) {
                float dv = silu_f(acc[nt][jj]);
                dlt[nt][jj] = dv;
                tbw[(lg * 4 + jj) * 72 + nt * 16 + lm] = (__bf16)dv;
            }

        // ---- stage C: next-chunk gathers (pos-delta + q-k), hide under A1/A2
        float pdlN[3];
        bf16x8 qmkN0, qmkN1;
        if (hn) {
            const float* ps = pos + (size_t)sN * 3;
            const float* pd = pos + (size_t)dN * 3;
            pdlN[0] = pd[0] - ps[0]; pdlN[1] = pd[1] - ps[1]; pdlN[2] = pd[2] - ps[2];
            const __bf16* qp = qqb + (size_t)dN * 64 + lg * 8;
            const __bf16* kp = kkb + (size_t)sN * 64 + lg * 8;
            bf16x8 q0 = *(const bf16x8*)qp, q1 = *(const bf16x8*)(qp + 32);
            bf16x8 k0 = *(const bf16x8*)kp, k1 = *(const bf16x8*)(kp + 32);
#pragma unroll
            for (int j = 0; j < 8; ++j) {
                qmkN0[j] = (__bf16)((float)q0[j] - (float)k0[j]);
                qmkN1[j] = (__bf16)((float)q1[j] - (float)k1[j]);
            }
        }

        // alpha0 = (q-k) + delta  (delta re-read in A-layout)
        bf16x8 dA0 = *(const bf16x8*)&tbw[lm * 72 + lg * 8];
        bf16x8 dA1 = *(const bf16x8*)&tbw[lm * 72 + 32 + lg * 8];
        bf16x8 aA0, aA1;
#pragma unroll
        for (int j = 0; j < 8; ++j) {
            aA0[j] = (__bf16)((float)qmk0[j] + (float)dA0[j]);
            aA1[j] = (__bf16)((float)qmk1[j] + (float)dA1[j]);
        }

        // ---- A1
#pragma unroll
        for (int nt = 0; nt < 4; ++nt) {
            f32x4 a; a[0] = a[1] = a[2] = a[3] = ab1r[nt];
            a = __builtin_amdgcn_mfma_f32_16x16x32_bf16(aA0, *(const bf16x8*)&Wtab[1][nt * 2 + 0][l][0], a, 0, 0, 0);
            a = __builtin_amdgcn_mfma_f32_16x16x32_bf16(aA1, *(const bf16x8*)&Wtab[1][nt * 2 + 1][l][0], a, 0, 0, 0);
            acc[nt] = a;
        }
#pragma unroll
        for (int nt = 0; nt < 4; ++nt)
#pragma unroll
            for (int jj = 0; jj < 4; ++jj)
                tbw[(lg * 4 + jj) * 72 + nt * 16 + lm] = (__bf16)silu_f(acc[nt][jj]);
        bf16x8 aY0 = *(const bf16x8*)&tbw[lm * 72 + lg * 8];
        bf16x8 aY1 = *(const bf16x8*)&tbw[lm * 72 + 32 + lg * 8];

        // ---- A2
#pragma unroll
        for (int nt = 0; nt < 4; ++nt) {
            f32x4 a; a[0] = a[1] = a[2] = a[3] = ab2r[nt];
            a = __builtin_amdgcn_mfma_f32_16x16x32_bf16(aY0, *(const bf16x8*)&Wtab[2][nt * 2 + 0][l][0], a, 0, 0, 0);
            a = __builtin_amdgcn_mfma_f32_16x16x32_bf16(aY1, *(const bf16x8*)&Wtab[2][nt * 2 + 1][l][0], a, 0, 0, 0);
            acc[nt] = a;
        }

        // ---- scatter: lane covers co = nt*16+lm for edge er = lg*4+jj
#pragma unroll
        for (int jj = 0; jj < 4; ++jj) {
            const int eD = e0 + lg * 4 + jj;
            if (eD < Etot) {
                const size_t ob = (size_t)dD[jj] * 64 + lm;
#pragma unroll
                for (int nt = 0; nt < 4; ++nt) {
                    float ex = __expf(silu_f(acc[nt][jj]));
                    atomicAdd(&den[ob + nt * 16], ex);
                    atomicAdd(&num[ob + nt * 16], ex * ((float)vpre[jj][nt] + dlt[nt][jj]));
                }
            }
        }

        if (!hn) break;
        sC = sN; dC = dN;
        pdl[0] = pdlN[0]; pdl[1] = pdlN[1]; pdl[2] = pdlN[2];
        qmk0 = qmkN0; qmk1 = qmkN1;
        ch = chn;
    }
}

// ---------------------------------------------------------------------------
// Kernel: pre = num/den; o = pre @ Wout + bout ; accumulate BN2 stats
// ---------------------------------------------------------------------------
__global__ __launch_bounds__(256) void k_out(
    const float* __restrict__ num, const float* __restrict__ den,
    const float* __restrict__ Wout, const float* __restrict__ bout,
    float* __restrict__ o, float* __restrict__ ssum, float* __restrict__ ssq, int N)
{
    __shared__ float xt[64 * 64];
    __shared__ float Wl[64 * 64];
    __shared__ float red[2][4][64];
    const int t = threadIdx.x, c = t & 63, g = t >> 6;
    const int row0 = blockIdx.x * 64;

    for (int i = t; i < 64 * 64; i += 256) {
        int r = i >> 6, cc = i & 63;
        int gr = row0 + r;
        xt[i] = (gr < N) ? num[(size_t)gr * CH + cc] / den[(size_t)gr * CH + cc] : 0.0f;
        Wl[i] = Wout[i];
    }
    __syncthreads();

    float acc[16];
    const float b = bout[c];
#pragma unroll
    for (int i = 0; i < 16; ++i) acc[i] = b;
    for (int k = 0; k < 64; ++k) {
        float w = Wl[k * 64 + c];
#pragma unroll
        for (int i = 0; i < 16; ++i) acc[i] += xt[(g * 16 + i) * 64 + k] * w;
    }
    float s = 0.0f, ss = 0.0f;
#pragma unroll
    for (int i = 0; i < 16; ++i) {
        int gr = row0 + g * 16 + i;
        if (gr < N) {
            o[(size_t)gr * CH + c] = acc[i];
            s += acc[i];
            ss += acc[i] * acc[i];
        }
    }
    red[0][g][c] = s;
    red[1][g][c] = ss;
    __syncthreads();
    if (g == 0) {
        atomicAdd(&ssum[c], red[0][0][c] + red[0][1][c] + red[0][2][c] + red[0][3][c]);
        atomicAdd(&ssq[c],  red[1][0][c] + red[1][1][c] + red[1][2][c] + red[1][3][c]);
    }
}

// ---------------------------------------------------------------------------
__global__ void k_final(const float* __restrict__ o, const float* __restrict__ scale,
                        const float* __restrict__ shift, float* __restrict__ out, int total)
{
    int i = blockIdx.x * blockDim.x + threadIdx.x;
    if (i < total) {
        int c = i & 63;
        out[i] = o[i] * scale[c] + shift[c];
    }
}

// ---------------------------------------------------------------------------
extern "C" void kernel_launch(void* const* d_in, const int* in_sizes, int n_in,
                              void* d_out, int out_size, void* d_ws, size_t ws_size,
                              hipStream_t stream)
{
    const float* x      = (const float*)d_in[0];
    const float* pos    = (const float*)d_in[1];
    const int*   ei     = (const int*)d_in[2];
    const float* Win    = (const float*)d_in[3];
    const float* bin    = (const float*)d_in[4];
    const float* gin    = (const float*)d_in[5];
    const float* betain = (const float*)d_in[6];
    const float* Wv     = (const float*)d_in[7];
    const float* Wk     = (const float*)d_in[8];
    const float* Wq     = (const float*)d_in[9];
    const float* P1     = (const float*)d_in[10];
    const float* pb1    = (const float*)d_in[11];
    const float* P2     = (const float*)d_in[12];
    const float* pb2    = (const float*)d_in[13];
    const float* A1     = (const float*)d_in[14];
    const float* ab1    = (const float*)d_in[15];
    const float* A2     = (const float*)d_in[16];
    const float* ab2    = (const float*)d_in[17];
    const float* Wout   = (const float*)d_in[18];
    const float* bout   = (const float*)d_in[19];
    const float* gout   = (const float*)d_in[20];
    const float* betaout= (const float*)d_in[21];

    const int N = in_sizes[0] / CH;
    const int E = in_sizes[2] / 2;
    const int Etot = E + N;
    const int* srcA = ei;
    const int* dstA = ei + E;

    float* ws = (float*)d_ws;
    const size_t NC = (size_t)N * CH;
    float* h    = ws;             // N*C f32 (reused as o after edge pass)
    float* num  = h + NC;         // N*C f32
    float* den  = num + NC;       // N*C f32
    float* st   = den + NC;       // 512 f32 stats
    __bf16* vvb = (__bf16*)(st + 512);  // N*C bf16
    __bf16* kkb = vvb + NC;             // N*C bf16
    __bf16* qqb = kkb + NC;             // N*C bf16

    // zero num, den, stats in one shot (contiguous)
    hipMemsetAsync(num, 0, (2 * NC + 512) * sizeof(float), stream);

    const int nb = (N + 63) / 64;
    k_lin_in<<<nb, 256, 0, stream>>>(x, Win, bin, h, st, st + 64, N);
    k_stats<<<1, 64, 0, stream>>>(st, st + 64, gin, betain, st + 128, st + 192, N);
    k_vkq<<<nb, 256, 0, stream>>>(h, st + 128, st + 192, Wv, Wk, Wq, vvb, kkb, qqb, N);

    const int nChunks = (Etot + 63) / 64;
    const int grid = (nChunks < 2048) ? nChunks : 2048;
    k_edge_mfma<<<grid, 256, 0, stream>>>(srcA, dstA, pos, vvb, kkb, qqb,
                                          P1, pb1, P2, pb2, A1, ab1, A2, ab2,
                                          num, den, E, Etot, nChunks);

    k_out<<<nb, 256, 0, stream>>>(num, den, Wout, bout, h, st + 256, st + 320, N);
    k_stats<<<1, 64, 0, stream>>>(st + 256, st + 320, gout, betaout, st + 384, st + 448, N);
    k_final<<<(int)((NC + 255) / 256), 256, 0, stream>>>(h, st + 384, st + 448,
                                                         (float*)d_out, (int)NC);
}